// Round 9
// baseline (528.137 us; speedup 1.0000x reference)
//
#include <hip/hip_runtime.h>

// GroupBatchNorm: B=512, C=65536, G=4096, fp32 in/out.
// R11: push the two big streamers toward their BW floors; kernel count and
// pipeline shape held at R10's (controlled experiment).
//   Model from R4..R10: dur_us ~= sum(kernels) + ~148 us fixed harness
//   component (calibrated by R6: fused kernel 290 us in rocprof vs 437.9
//   dur_us). Kernel sum ~130 us vs ~55 us roofline. Remaining suspects:
//   - R10 stats_k ran at 1 block/CU (256 blocks)   -> now 2048 (8/CU)
//   - norm_k was 32768 single-float4 micro-blocks  -> now 2048 grid-stride
//     blocks, 16 float4/thread, 8-deep load batches, scale/shift table
//     loaded ONCE per thread (fixed channel-quad; cfinal path kept -- R7
//     showed inline gather in the streamer costs ~21 us).
//   - atomics vs partials proven neutral (R8 278.6 vs R10 279.9): keep
//     atomics, 4.2M over 12 KB; hot-address chain = 512 serial RMW ~ us.

constexpr int B = 512;
constexpr int C = 65536;
constexpr int G = 4096;
constexpr int Q = C / 4;            // 16384 channel-quads (pow2)
constexpr int CHUNKS = 32;          // row chunks in stats_k
constexpr int RPC = B / CHUNKS;     // 16 rows per chunk
constexpr int BATCH = 8;            // float4 loads in flight per thread
#define EPS 1e-5f

// Device-global scratch. Zeroed by zero_k at the start of EVERY launch
// sequence -- no cross-launch state (R9 tripwire lesson).
__device__ float g_gsum[G];
__device__ float g_gsum2[G];
__device__ float g_gcnt[G];
__device__ float g_cscale[C];
__device__ float g_cshift[C];

// ---- K0: zero group accumulators. grid = 16 blocks.
__global__ __launch_bounds__(256) void zero_k() {
    int i = blockIdx.x * 256 + threadIdx.x;
    if (i < G) {
        g_gsum[i] = 0.0f;
        g_gsum2[i] = 0.0f;
        g_gcnt[i] = 0.0f;
    }
}

// ---- K1: fused colsum+gsum. grid = 64 col-blocks x 32 chunks = 2048
// blocks (8/CU). Thread reduces its 4 channels over 16 rows in registers
// (two 8-deep float4 batches), then 8 global atomics.
__global__ __launch_bounds__(256) void stats_k(const float* __restrict__ x,
                                               const int* __restrict__ cg) {
    const int nblk_c = Q / 256;                                // 64
    const int c4 = (blockIdx.x % nblk_c) * 256 + threadIdx.x;  // channel-quad
    const int chunk = blockIdx.x / nblk_c;                     // 32 chunks
    const float4* __restrict__ xp =
        (const float4*)(x + (size_t)chunk * RPC * C) + c4;
    float4 s = {0.f, 0.f, 0.f, 0.f};
    float4 s2 = {0.f, 0.f, 0.f, 0.f};
    float4 vbuf[BATCH];
    for (int base = 0; base < RPC; base += BATCH) {
#pragma unroll
        for (int j = 0; j < BATCH; ++j)
            vbuf[j] = xp[(size_t)(base + j) * Q];
#pragma unroll
        for (int j = 0; j < BATCH; ++j) {
            float4 v = vbuf[j];
            s.x += v.x; s.y += v.y; s.z += v.z; s.w += v.w;
            s2.x = fmaf(v.x, v.x, s2.x);
            s2.y = fmaf(v.y, v.y, s2.y);
            s2.z = fmaf(v.z, v.z, s2.z);
            s2.w = fmaf(v.w, v.w, s2.w);
        }
    }
    const int4 gq = ((const int4*)cg)[c4];
    atomicAdd(&g_gsum[gq.x], s.x);  atomicAdd(&g_gsum2[gq.x], s2.x);
    atomicAdd(&g_gsum[gq.y], s.y);  atomicAdd(&g_gsum2[gq.y], s2.y);
    atomicAdd(&g_gsum[gq.z], s.z);  atomicAdd(&g_gsum2[gq.z], s2.z);
    atomicAdd(&g_gsum[gq.w], s.w);  atomicAdd(&g_gsum2[gq.w], s2.w);
    if (chunk == 0) {
        atomicAdd(&g_gcnt[gq.x], 1.0f);
        atomicAdd(&g_gcnt[gq.y], 1.0f);
        atomicAdd(&g_gcnt[gq.z], 1.0f);
        atomicAdd(&g_gcnt[gq.w], 1.0f);
    }
}

// ---- K2: per-channel fused scale/shift (gather ONCE per channel).
__global__ __launch_bounds__(256) void cfinal_k(const int* __restrict__ cg,
                                                const float* __restrict__ gamma,
                                                const float* __restrict__ beta) {
    const int c = blockIdx.x * 256 + threadIdx.x;
    const int g = cg[c];
    float cnt = fmaxf(g_gcnt[g] * (float)B, 1.0f);
    float mean = g_gsum[g] / cnt;
    float var = g_gsum2[g] / cnt - mean * mean;
    float inv = 1.0f / sqrtf(var + EPS);
    float sc = gamma[g] * inv;
    g_cscale[c] = sc;
    g_cshift[c] = fmaf(-mean, sc, beta[g]);
}

// ---- K3: streaming normalize, grid-stride. 2048 blocks -> NT = 524288
// threads; stride NT is a multiple of Q so each thread's channel-quad is
// FIXED: load scale/shift from the L2-hot tables ONCE, then 16 float4
// iterations in two 8-deep batches. Stateless.
constexpr int NT3 = 2048 * 256;
__global__ __launch_bounds__(256) void norm_k(const float* __restrict__ x,
                                              float* __restrict__ out) {
    const int n = blockIdx.x * 256 + threadIdx.x;
    const int c4 = n & (Q - 1);
    const float4 sc = ((const float4*)g_cscale)[c4];
    const float4 sh = ((const float4*)g_cshift)[c4];
    const float4* __restrict__ xin = (const float4*)x;
    float4* __restrict__ op = (float4*)out;
    constexpr int ITERS = (B * (C / 4)) / NT3;  // 16
    float4 vbuf[BATCH];
#pragma unroll 1
    for (int base = 0; base < ITERS; base += BATCH) {
#pragma unroll
        for (int j = 0; j < BATCH; ++j)
            vbuf[j] = xin[(size_t)(base + j) * NT3 + n];
#pragma unroll
        for (int j = 0; j < BATCH; ++j) {
            float4 v = vbuf[j];
            float4 o;
            o.x = fmaf(v.x, sc.x, sh.x);
            o.y = fmaf(v.y, sc.y, sh.y);
            o.z = fmaf(v.z, sc.z, sh.z);
            o.w = fmaf(v.w, sc.w, sh.w);
            op[(size_t)(base + j) * NT3 + n] = o;
        }
    }
}

extern "C" void kernel_launch(void* const* d_in, const int* in_sizes, int n_in,
                              void* d_out, int out_size, void* d_ws, size_t ws_size,
                              hipStream_t stream) {
    const float* x = (const float*)d_in[0];
    const int* cg = (const int*)d_in[1];
    const float* gamma = (const float*)d_in[2];
    const float* beta = (const float*)d_in[3];
    float* out = (float*)d_out;
    (void)d_ws; (void)ws_size; (void)in_sizes; (void)n_in; (void)out_size;

    zero_k<<<(G + 255) / 256, 256, 0, stream>>>();
    stats_k<<<(Q / 256) * CHUNKS, 256, 0, stream>>>(x, cg);
    cfinal_k<<<C / 256, 256, 0, stream>>>(cg, gamma, beta);
    norm_k<<<NT3 / 256, 256, 0, stream>>>(x, out);
}